// Round 5
// baseline (291.203 us; speedup 1.0000x reference)
//
#include <hip/hip_runtime.h>
#include <hip/hip_bf16.h>

// EncoderBlock: B=2, N=4096, D=256, H=8, HD=32, DFF=1024.
// I/O fp32; internal bf16 MFMA. Attention: split-K flash, no-max log2 softmax
// (scores bounded => exp2 fp32-safe; softmax invariant to the missing max).
#define Bb 2
#define Nn 4096
#define Dd 256
#define Hh 8
#define HDh 32
#define DFFd 1024
#define MT (Bb*Nn)   // 8192 rows
#define Tt ((size_t)MT * Dd)
#define SPLIT 4
#define KVB (Nn / SPLIT)

typedef __attribute__((ext_vector_type(8))) short short8;
typedef __attribute__((ext_vector_type(4))) float f32x4;
typedef __attribute__((address_space(1))) const unsigned int gu32;
typedef __attribute__((address_space(3))) unsigned int lu32;

__device__ __forceinline__ void gll16(const ushort* g, ushort* l) {
  // async global->LDS, 16B/lane; LDS dest = wave-uniform base + lane*16
  __builtin_amdgcn_global_load_lds((gu32*)g, (lu32*)l, 16, 0, 0);
}
__device__ __forceinline__ float bf2f(ushort u){
  union { unsigned int i; float f; } v; v.i = ((unsigned int)u) << 16; return v.f;
}
__device__ __forceinline__ ushort f2bf(float f){           // RNE
  union { float f; unsigned int i; } v; v.f = f;
  unsigned int r = v.i + 0x7fffu + ((v.i >> 16) & 1u);
  return (ushort)(r >> 16);
}

// ---- prep: fp32 weights -> bf16 transposed WT[n][k]; concat qkv bias -------
__global__ __launch_bounds__(256) void prep_kernel(
    const float* __restrict__ Wq, const float* __restrict__ Wk,
    const float* __restrict__ Wv, const float* __restrict__ Wo,
    const float* __restrict__ W1, const float* __restrict__ W2,
    const float* __restrict__ bq, const float* __restrict__ bk,
    const float* __restrict__ bv, ushort* __restrict__ wt,
    float* __restrict__ bqkv)
{
  if (blockIdx.x == 768) {
    const int t = threadIdx.x;
    bqkv[t] = bq[t]; bqkv[256 + t] = bk[t]; bqkv[512 + t] = bv[t];
    return;
  }
  const int base = (blockIdx.x * 256 + threadIdx.x) * 4;   // [0, 786432)
  const float* src; int k0, Ns;
  if (base < 196608) {                       // WTqkv[768][256]
    const int n = base >> 8; k0 = base & 255;
    const int w = n >> 8, cn = n & 255;
    src = (w == 0 ? Wq : w == 1 ? Wk : Wv) + cn; Ns = 256;
  } else if (base < 262144) {                // WTo[256][256]
    const int off = base - 196608;
    src = Wo + (off >> 8); k0 = off & 255; Ns = 256;
  } else if (base < 524288) {                // WT1[1024][256]
    const int off = base - 262144;
    src = W1 + (off >> 8); k0 = off & 255; Ns = 1024;
  } else {                                   // WT2[256][1024]
    const int off = base - 524288;
    src = W2 + (off >> 10); k0 = off & 1023; Ns = 256;
  }
  ushort4 o;
  o.x = f2bf(src[(size_t)(k0 + 0) * Ns]);
  o.y = f2bf(src[(size_t)(k0 + 1) * Ns]);
  o.z = f2bf(src[(size_t)(k0 + 2) * Ns]);
  o.w = f2bf(src[(size_t)(k0 + 3) * Ns]);
  *(ushort4*)(wt + base) = o;
}

// ---- LayerNorm: (x-mean)/(std+1e-6); fp32 in, bf16 out; wave per row -------
__global__ __launch_bounds__(256) void ln_kernel(const float* __restrict__ x,
                                                 ushort* __restrict__ out)
{
  const int wave = threadIdx.x >> 6, lane = threadIdx.x & 63;
  const int row = blockIdx.x * 4 + wave;
  const float4 u = *(const float4*)(x + (size_t)row * Dd + lane * 4);
  float s1 = u.x + u.y + u.z + u.w;
  float s2 = u.x*u.x + u.y*u.y + u.z*u.z + u.w*u.w;
  #pragma unroll
  for (int m = 1; m < 64; m <<= 1) { s1 += __shfl_xor(s1, m, 64); s2 += __shfl_xor(s2, m, 64); }
  const float mean = s1 * (1.0f / Dd);
  float var = s2 * (1.0f / Dd) - mean * mean;
  var = var < 0.f ? 0.f : var;
  const float inv = 1.0f / (sqrtf(var) + 1e-6f);
  ushort4 o;
  o.x = f2bf((u.x - mean) * inv); o.y = f2bf((u.y - mean) * inv);
  o.z = f2bf((u.z - mean) * inv); o.w = f2bf((u.w - mean) * inv);
  *(ushort4*)(out + (size_t)row * Dd + lane * 4) = o;
}

// ---- 64x32-tile MFMA GEMM via global_load_lds; BT[n][k] input --------------
// EPI 0: QKV fused (N=768): q scaled by log2e/sqrt(32), q/k -> [b,h,n,hd],
//        v -> transposed [b,h,hd,n]
// EPI 1: + fp32 residual, fp32 out
// EPI 2: gelu(tanh), bf16 out
template<int EPI>
__global__ __launch_bounds__(256) void gemm_epi(
    const ushort* __restrict__ A, const ushort* __restrict__ BT,
    const float* __restrict__ bias, const float* __restrict__ res,
    void* __restrict__ outv, int N, int K)
{
  __shared__ __align__(16) ushort As[64][32];
  __shared__ __align__(16) ushort Bs[32][32];
  const int tid = threadIdx.x;
  const int wave = tid >> 6, lane = tid & 63;
  const int quad = lane >> 4, l15 = lane & 15;
  const int n0 = blockIdx.x * 32, m0 = blockIdx.y * 64;
  f32x4 acc[2];
  acc[0] = (f32x4){0.f,0.f,0.f,0.f}; acc[1] = (f32x4){0.f,0.f,0.f,0.f};
  const int lr = lane >> 2, lc = (lane & 3) * 8;
  const ushort* ag = A + (size_t)(m0 + wave * 16 + lr) * K + lc;
  ushort* als = &As[wave * 16][0];
  const ushort* bg = BT + (size_t)(n0 + (wave & 1) * 16 + lr) * K + lc;  // waves 0,1 only
  ushort* bls = &Bs[(wave & 1) * 16][0];
  for (int k0 = 0; k0 < K; k0 += 32) {
    __syncthreads();
    gll16(ag + k0, als);
    if (wave < 2) gll16(bg + k0, bls);
    __syncthreads();
    const short8 af = *(const short8*)(&As[wave * 16 + l15][quad * 8]);
    const short8 bf0 = *(const short8*)(&Bs[l15][quad * 8]);
    const short8 bf1 = *(const short8*)(&Bs[16 + l15][quad * 8]);
    acc[0] = __builtin_amdgcn_mfma_f32_16x16x32_bf16(af, bf0, acc[0], 0, 0, 0);
    acc[1] = __builtin_amdgcn_mfma_f32_16x16x32_bf16(af, bf1, acc[1], 0, 0, 0);
  }
  const int row0 = m0 + wave * 16 + quad * 4;
  #pragma unroll
  for (int nt = 0; nt < 2; nt++) {
    const int col = n0 + nt * 16 + l15;
    const float bv = bias[col];
    float c[4];
    #pragma unroll
    for (int i = 0; i < 4; i++) c[i] = acc[nt][i] + bv;
    if (EPI == 0) {
      ushort* qkv = (ushort*)outv;
      const int w = col >> 8, cd = col & 255;
      const int h = cd >> 5, hd = cd & 31;
      const int b = row0 >> 12, n = row0 & (Nn - 1);
      if (w < 2) {
        const float sc = (w == 0) ? (1.4426950408889634f * 0.17677669529663687f) : 1.0f;
        ushort* dst = qkv + (size_t)w * Tt + ((size_t)((b * Hh + h) * Nn) + n) * HDh + hd;
        #pragma unroll
        for (int i = 0; i < 4; i++) dst[(size_t)i * HDh] = f2bf(c[i] * sc);
      } else {   // V transposed: [b,h,hd,n], 4 consecutive n -> ushort4
        ushort4 pk;
        pk.x = f2bf(c[0]); pk.y = f2bf(c[1]); pk.z = f2bf(c[2]); pk.w = f2bf(c[3]);
        *(ushort4*)(qkv + 2 * Tt + ((size_t)((b * Hh + h) * HDh + hd)) * Nn + n) = pk;
      }
    } else if (EPI == 1) {
      float* out = (float*)outv;
      #pragma unroll
      for (int i = 0; i < 4; i++) {
        const size_t idx = (size_t)(row0 + i) * N + col;
        out[idx] = c[i] + res[idx];
      }
    } else {
      ushort* out = (ushort*)outv;
      #pragma unroll
      for (int i = 0; i < 4; i++) {
        const float t = tanhf(0.7978845608028654f * (c[i] + 0.044715f * c[i] * c[i] * c[i]));
        out[(size_t)(row0 + i) * N + col] = f2bf(0.5f * c[i] * (1.0f + t));
      }
    }
  }
}

// ---- Flash attention, split-K, no-max: S^T = K Q^T (Q pre-scaled),
// p = exp2(s), O^T += V^T P^T; partials atomicAdd'ed into Oacc/lacc ---------
__global__ __launch_bounds__(256) void attn_kernel(
    const ushort* __restrict__ qp, const ushort* __restrict__ kp,
    const ushort* __restrict__ vtg, float* __restrict__ Oacc,
    float* __restrict__ lacc)
{
  __shared__ __align__(16) ushort Ks[64][32];      // K tile [kv][d], gll dest
  __shared__ __align__(16) ushort Vt[32][72];      // V^T tile [d][kv=64] (+pad; 40 was an
                                                   // overlapping-row bug: d*40+kv not injective)
  __shared__ __align__(16) ushort Ps[4][16][72];   // per-wave P^T round-trip
  const int tid = threadIdx.x;
  const int wave = tid >> 6, lane = tid & 63;
  const int quad = lane >> 4, l15 = lane & 15;
  const int qt = blockIdx.x, bh = blockIdx.y, sp = blockIdx.z;
  const size_t base = (size_t)bh * Nn * HDh;
  const int qrow = qt * 64 + wave * 16 + l15;
  const short8 qf = *(const short8*)(qp + base + (size_t)qrow * HDh + quad * 8);
  const int kv_begin = sp * KVB;
  const ushort* kg = kp + base + (size_t)(kv_begin + wave * 16 + (lane >> 2)) * HDh + (lane & 3) * 8;
  ushort* kls = &Ks[wave * 16][0];
  const int vd = tid >> 3, vc = (tid & 7) * 8;
  const ushort* vg = vtg + ((size_t)bh * HDh + vd) * Nn + kv_begin + vc;
  f32x4 o0 = {0.f,0.f,0.f,0.f}, o1 = {0.f,0.f,0.f,0.f};   // O^T: d=quad*4+i(+16), q=l15
  float rs = 0.f;                                          // per-lane partial of l
  const f32x4 zero4 = {0.f,0.f,0.f,0.f};
  for (int step = 0; step < KVB / 64; step++) {
    __syncthreads();
    gll16(kg, kls);
    const int4 vv = *(const int4*)vg;
    kg += 64 * HDh; vg += 64;
    *(int4*)(&Vt[vd][vc]) = vv;
    __syncthreads();
    f32x4 s[4];
    #pragma unroll
    for (int nt = 0; nt < 4; nt++) {
      const short8 kf = *(const short8*)(&Ks[nt * 16 + l15][quad * 8]);
      s[nt] = __builtin_amdgcn_mfma_f32_16x16x32_bf16(kf, qf, zero4, 0, 0, 0);
    }
    #pragma unroll
    for (int nt = 0; nt < 4; nt++) {
      const float p0 = __builtin_amdgcn_exp2f(s[nt][0]);
      const float p1 = __builtin_amdgcn_exp2f(s[nt][1]);
      const float p2 = __builtin_amdgcn_exp2f(s[nt][2]);
      const float p3 = __builtin_amdgcn_exp2f(s[nt][3]);
      rs += (p0 + p1) + (p2 + p3);
      const unsigned int u0 = __float_as_uint(p0) + 0x8000u;
      const unsigned int u1 = __float_as_uint(p1) + 0x8000u;
      const unsigned int u2 = __float_as_uint(p2) + 0x8000u;
      const unsigned int u3 = __float_as_uint(p3) + 0x8000u;
      uint2 pk;
      pk.x = __builtin_amdgcn_perm(u1, u0, 0x07060302u);   // bf(p1)|bf(p0)
      pk.y = __builtin_amdgcn_perm(u3, u2, 0x07060302u);
      *(uint2*)(&Ps[wave][l15][nt * 16 + quad * 4]) = pk;
    }
    __builtin_amdgcn_wave_barrier();   // Ps wave-local; DS in-order per wave
    #pragma unroll
    for (int ks = 0; ks < 2; ks++) {
      const short8 pf = *(const short8*)(&Ps[wave][l15][ks * 32 + quad * 8]);
      const short8 v0 = *(const short8*)(&Vt[l15][ks * 32 + quad * 8]);
      const short8 v1 = *(const short8*)(&Vt[16 + l15][ks * 32 + quad * 8]);
      o0 = __builtin_amdgcn_mfma_f32_16x16x32_bf16(v0, pf, o0, 0, 0, 0);
      o1 = __builtin_amdgcn_mfma_f32_16x16x32_bf16(v1, pf, o1, 0, 0, 0);
    }
    __builtin_amdgcn_wave_barrier();
  }
  rs += __shfl_xor(rs, 16, 64);
  rs += __shfl_xor(rs, 32, 64);
  const int n = qt * 64 + wave * 16 + l15;
  float* op = Oacc + ((size_t)bh * Nn + n) * HDh;
  #pragma unroll
  for (int i = 0; i < 4; i++) {
    atomicAdd(op + quad * 4 + i, o0[i]);
    atomicAdd(op + 16 + quad * 4 + i, o1[i]);
  }
  if (quad == 0) atomicAdd(lacc + (size_t)bh * Nn + n, rs);
}

// ---- normalize O by l, regather to [B,N,D] bf16 ----------------------------
__global__ __launch_bounds__(256) void attn_norm(const float* __restrict__ Oacc,
    const float* __restrict__ lacc, ushort* __restrict__ attn)
{
  const int idx = blockIdx.x * 256 + threadIdx.x;    // over [16][4096][8]
  const int d4 = idx & 7, rest = idx >> 3;
  const int n = rest & (Nn - 1), bh = rest >> 12;
  const float4 ov = *(const float4*)(Oacc + ((size_t)bh * Nn + n) * HDh + d4 * 4);
  const float inv = 1.0f / lacc[(size_t)bh * Nn + n];
  ushort4 o;
  o.x = f2bf(ov.x * inv); o.y = f2bf(ov.y * inv);
  o.z = f2bf(ov.z * inv); o.w = f2bf(ov.w * inv);
  const int b = bh >> 3, h = bh & 7;
  *(ushort4*)(attn + ((size_t)(b * Nn + n)) * Dd + h * HDh + d4 * 4) = o;
}

extern "C" void kernel_launch(void* const* d_in, const int* in_sizes, int n_in,
                              void* d_out, int out_size, void* d_ws, size_t ws_size,
                              hipStream_t stream)
{
  const float* x  = (const float*)d_in[0];
  const float* Wq = (const float*)d_in[1];
  const float* bq = (const float*)d_in[2];
  const float* Wk = (const float*)d_in[3];
  const float* bk = (const float*)d_in[4];
  const float* Wv = (const float*)d_in[5];
  const float* bv = (const float*)d_in[6];
  const float* Wo = (const float*)d_in[7];
  const float* bo = (const float*)d_in[8];
  const float* W1 = (const float*)d_in[9];
  const float* b1 = (const float*)d_in[10];
  const float* W2 = (const float*)d_in[11];
  const float* b2 = (const float*)d_in[12];

  char* ws = (char*)d_ws;
  ushort* wt    = (ushort*)ws;                       // 786432 bf16
  ushort* wtqkv = wt;
  ushort* wto   = wt + 196608;
  ushort* wt1   = wt + 262144;
  ushort* wt2   = wt + 524288;
  float*  bqkv  = (float*)(ws + 786432 * 2);
  ushort* s0    = (ushort*)(ws + 786432 * 2 + 4096); // 4 MiB slots
  ushort* s1    = s0 + Tt;                           // q [b,h,n,hd]
  ushort* s2    = s1 + Tt;                           // k [b,h,n,hd]
  ushort* s3    = s2 + Tt;                           // v [b,h,hd,n]
  float*  xsk   = (float*)(s3 + Tt);                 // fp32 8 MiB; Oacc during attn
  ushort* xn2   = (ushort*)(xsk + Tt);               // bf16 4 MiB; lacc (256KB) during attn
  ushort* xn1   = s0;
  ushort* attn  = s0;
  ushort* hid   = s0;                                // 16 MiB spans s0..s3
  float*  Oacc  = xsk;
  float*  lacc  = (float*)xn2;
  float*  outp  = (float*)d_out;

  const dim3 blk(256);
  hipLaunchKernelGGL(prep_kernel, dim3(769), blk, 0, stream,
                     Wq, Wk, Wv, Wo, W1, W2, bq, bk, bv, wt, bqkv);
  hipLaunchKernelGGL(ln_kernel, dim3(MT / 4), blk, 0, stream, x, xn1);
  hipLaunchKernelGGL((gemm_epi<0>), dim3(24, 128), blk, 0, stream,
                     xn1, wtqkv, bqkv, (const float*)nullptr, (void*)s1, 768, Dd);

  hipMemsetAsync(Oacc, 0, Tt * sizeof(float) + (size_t)Bb * Hh * Nn * sizeof(float), stream);
  hipLaunchKernelGGL(attn_kernel, dim3(Nn / 64, Bb * Hh, SPLIT), blk, 0, stream,
                     s1, s2, s3, Oacc, lacc);
  hipLaunchKernelGGL(attn_norm, dim3((Bb * Hh * Nn * 8) / 256), blk, 0, stream,
                     Oacc, lacc, attn);

  hipLaunchKernelGGL((gemm_epi<1>), dim3(8, 128), blk, 0, stream,
                     attn, wto, bo, x, (void*)xsk, Dd, Dd);
  hipLaunchKernelGGL(ln_kernel, dim3(MT / 4), blk, 0, stream, xsk, xn2);
  hipLaunchKernelGGL((gemm_epi<2>), dim3(32, 128), blk, 0, stream,
                     xn2, wt1, b1, (const float*)nullptr, (void*)hid, DFFd, Dd);
  hipLaunchKernelGGL((gemm_epi<1>), dim3(8, 128), blk, 0, stream,
                     hid, wt2, b2, xsk, (void*)outp, Dd, DFFd);
}